// Round 15
// baseline (154.164 us; speedup 1.0000x reference)
//
#include <hip/hip_runtime.h>

typedef __attribute__((ext_vector_type(4))) int i32x4;

#define AS1 __attribute__((address_space(1)))
#define AS3 __attribute__((address_space(3)))

constexpr int MDIM = 8192;   // batch
constexpr int NDIM = 4096;   // out features
constexpr int KDIM = 4096;   // in features

constexpr int BM = 256, BN = 256, BKB = 128;   // BKB = K-bytes (=128 i8) per tile
constexpr int NKT = KDIM / BKB;                // 32
constexpr int REP_CH = 528;                    // global table: 16-B chunks per replica
constexpr int WIN_CH = 273;                    // LDS window: 272 data chunks + 1 pad

__device__ __forceinline__ void gld_lds16(const signed char* g, signed char* l) {
  __builtin_amdgcn_global_load_lds((const AS1 void*)g, (AS3 void*)l, 16, 0, 0);
}

__device__ __forceinline__ int q8(float v, float inv) {
  return __float2int_rn(v * inv);
}

// ---- prep: w scale + 16-way byte-shift replica table (global) ----
__global__ __launch_bounds__(256) void prep_kernel(
    const float* __restrict__ params, float* __restrict__ swbuf,
    i32x4* __restrict__ rep16) {
  __shared__ signed char pql[8480];
  __shared__ float red[4];
  int t = (int)threadIdx.x;
  float m = 0.f;
  for (int i = t; i < NDIM + KDIM - 1; i += 256) m = fmaxf(m, fabsf(params[i]));
#pragma unroll
  for (int off = 32; off >= 1; off >>= 1) m = fmaxf(m, __shfl_xor(m, off));
  if ((t & 63) == 0) red[t >> 6] = m;
  __syncthreads();
  m = fmaxf(fmaxf(red[0], red[1]), fmaxf(red[2], red[3]));
  m = fmaxf(m, 1e-30f);
  float inv = 127.0f / m;
  if (t == 0) swbuf[0] = m * (1.0f / 127.0f);
  for (int i = t; i < 8480; i += 256)
    pql[i] = (i < NDIM + KDIM - 1) ? (signed char)q8(params[i], inv) : (signed char)0;
  __syncthreads();
  for (int idx = t; idx < 16 * REP_CH; idx += 256) {
    int r = idx / REP_CH, j = idx - r * REP_CH;
    const signed char* s = &pql[16 * j + r];
    i32x4 w;
#pragma unroll
    for (int d = 0; d < 4; ++d) {
      int b0 = (unsigned char)s[4 * d + 0];
      int b1 = (unsigned char)s[4 * d + 1];
      int b2 = (unsigned char)s[4 * d + 2];
      int b3 = (unsigned char)s[4 * d + 3];
      w[d] = b0 | (b1 << 8) | (b2 << 16) | (b3 << 24);
    }
    rep16[idx] = w;
  }
}

// ---- per-row x quantization: one block per row ----
__global__ __launch_bounds__(256) void quant_x_kernel(
    const float* __restrict__ x, signed char* __restrict__ xq, float* __restrict__ sxr) {
  int row = (int)blockIdx.x;
  int t = (int)threadIdx.x;
  const float4* px = (const float4*)(x + (size_t)row * KDIM) + t * 4;
  float4 v[4];
#pragma unroll
  for (int i = 0; i < 4; ++i) v[i] = px[i];
  float m = 0.f;
#pragma unroll
  for (int i = 0; i < 4; ++i)
    m = fmaxf(fmaxf(fmaxf(fabsf(v[i].x), fabsf(v[i].y)), fmaxf(fabsf(v[i].z), fabsf(v[i].w))), m);
#pragma unroll
  for (int off = 32; off >= 1; off >>= 1) m = fmaxf(m, __shfl_xor(m, off));
  __shared__ float red[4];
  if ((t & 63) == 0) red[t >> 6] = m;
  __syncthreads();
  m = fmaxf(fmaxf(red[0], red[1]), fmaxf(red[2], red[3]));
  m = fmaxf(m, 1e-30f);
  float inv = 127.0f / m;
  if (t == 0) sxr[row] = m * (1.0f / 127.0f);
  i32x4 w;
#pragma unroll
  for (int i = 0; i < 4; ++i) {
    int q0 = q8(v[i].x, inv), q1 = q8(v[i].y, inv), q2 = q8(v[i].z, inv), q3 = q8(v[i].w, inv);
    w[i] = (q0 & 0xff) | ((q1 & 0xff) << 8) | ((q2 & 0xff) << 16) | ((q3 & 0xff) << 24);
  }
  *(i32x4*)(xq + (size_t)row * KDIM + t * 16) = w;
}

// ========== 256x256 i8 GEMM, persistent-pair, 2-phase tile (4 sync points) ==========
// R14's data paths; per tile: lgkm(8) -> Q00+Q01 ; lgkm(0) -> Q10,Q11 ;
// vmcnt(0) -> BAR. Entry set [bvA4 bvB4 avA8] pre-issued (bv pre-BAR, avA post-BAR).
__global__ __launch_bounds__(512, 2) void toep_gemm_i8(
    const signed char* __restrict__ A,
    const i32x4* __restrict__ rep16,
    const float* __restrict__ bias,
    const float* __restrict__ sxr,
    const float* __restrict__ swbuf,
    float* __restrict__ C)
{
  __shared__ signed char sA[2][BM * BKB];          // 65536 B
  __shared__ signed char sPQ[16 * WIN_CH * 16];    // 69888 B

  constexpr int NBN = NDIM / BN;   // 16
  constexpr int NWG = (MDIM / BM / 2) * NBN;   // 256 (divisible by 8 -> bijective swizzle)
  int bid = (int)blockIdx.x;
  int swz = (bid & 7) * (NWG >> 3) + (bid >> 3);
  int bp = swz >> 4;              // M-pair index [0,16)
  int bn = swz & 15;
  int n0 = bn * BN;

  int t = (int)threadIdx.x;
  int lane = t & 63, wid = t >> 6;
  int wm = wid >> 2, wn = wid & 3;     // 2 (M) x 4 (N) waves; 128x64 per wave
  int lr = lane & 15, lk = lane >> 4;

  int scol = (((t & 7) ^ ((t >> 3) & 7)) << 4);   // bytes

  int aswz = (lr & 7) << 4;
  int c0 = (lk * 16) ^ aswz;        // k-bytes 0..63
  int c1 = (64 + lk * 16) ^ aswz;   // k-bytes 64..127

  int j0 = (3840 - n0) >> 4;
  int idx0 = 4095 - (n0 + wn * 64 + lr) + lk * 16;
  const signed char* pBbase = &sPQ[((idx0 & 15) * WIN_CH + ((idx0 >> 4) - j0) - 3) * 16];

  i32x4 avA[4][2], avB[4][2];
  i32x4 bvA[2][2], bvB[2][2];
  i32x4 acc[8][4];

#define STG_A(c, kt, R0) gld_lds16(gA + (size_t)(R0) * KDIM + (kt) * BKB, &sA[c][(R0) * BKB + t * 16])

#define LDA_GRP(c, msub, AV) do { \
  _Pragma("unroll") \
  for (int mi = 0; mi < 4; ++mi) { \
    const signed char* p_ = &sA[c][(wm * 128 + (msub) * 64 + mi * 16 + lr) * BKB]; \
    AV[mi][0] = *(const i32x4*)(p_ + c0); \
    AV[mi][1] = *(const i32x4*)(p_ + c1); \
  } } while (0)

#define LDB_GRP(BV, NSUB, PBP) do { \
  _Pragma("unroll") \
  for (int ni = 0; ni < 2; ++ni) \
    _Pragma("unroll") \
    for (int h = 0; h < 2; ++h) \
      BV[ni][h] = *(const i32x4*)((PBP) + (3 - 2 * (NSUB) - ni + 4 * h) * 16); \
} while (0)

// one quadrant, NO setprio (caller wraps)
#define MMA_Q(msub, nsub, AV, BV) do { \
  _Pragma("unroll") \
  for (int mi = 0; mi < 4; ++mi) \
    _Pragma("unroll") \
    for (int ni = 0; ni < 2; ++ni) { \
      acc[(msub) * 4 + mi][(nsub) * 2 + ni] = __builtin_amdgcn_mfma_i32_16x16x64_i8( \
          AV[mi][0], BV[ni][0], acc[(msub) * 4 + mi][(nsub) * 2 + ni], 0, 0, 0); \
      acc[(msub) * 4 + mi][(nsub) * 2 + ni] = __builtin_amdgcn_mfma_i32_16x16x64_i8( \
          AV[mi][1], BV[ni][1], acc[(msub) * 4 + mi][(nsub) * 2 + ni], 0, 0, 0); \
    } \
} while (0)

#define PRIO1() __builtin_amdgcn_s_setprio(1)
#define PRIO0() __builtin_amdgcn_s_setprio(0)
#define SB0() __builtin_amdgcn_sched_barrier(0)
#define BAR() __builtin_amdgcn_s_barrier()

  // Stage pq window ONCE per block (both subtiles share n0).
  for (int s = 0; s < 9; ++s) {
    int cc = s * 512 + t;
    if (cc < 16 * WIN_CH) {
      int rr = (int)(((unsigned long long)(unsigned)cc * 15732791ull) >> 32);  // cc/273
      int jj = cc - rr * WIN_CH;
      gld_lds16((const signed char*)(rep16 + rr * REP_CH + j0 + jj), &sPQ[cc * 16]);
    }
  }

  float sw = swbuf[0];

  // 2-phase tile. DS FIFO: entry [bvA4 bvB4 avA8]=16; +avB8 -> lgkm(8) drains entry;
  // lgkm(0) drains avB (cover = 32 MFMA). bvA' after Q10, bvB' after Q11 (reg-WAR via
  // in-order issue; same class as R13). vmcnt(0) drains DMA4 (issued P0, ~2600 cyc old).
  // avA' post-BAR only (other waves' DMA into buf c^1 guaranteed by vmcnt(0)+BAR).
#define TILE(c, kt) do { \
  const bool st_ = (kt) + 1 < NKT; \
  LDA_GRP(c, 1, avB); SB0(); \
  if (st_) { STG_A((c) ^ 1, (kt) + 1, 0); STG_A((c) ^ 1, (kt) + 1, 64); \
             STG_A((c) ^ 1, (kt) + 1, 128); STG_A((c) ^ 1, (kt) + 1, 192); SB0(); } \
  asm volatile("s_waitcnt lgkmcnt(8)" ::: "memory"); SB0(); \
  PRIO1(); MMA_Q(0, 0, avA, bvA); MMA_Q(0, 1, avA, bvB); PRIO0(); \
  asm volatile("s_waitcnt lgkmcnt(0)" ::: "memory"); SB0(); \
  PRIO1(); MMA_Q(1, 0, avB, bvA); PRIO0(); \
  if (st_) { LDB_GRP(bvA, 0, pB + 128); SB0(); } \
  PRIO1(); MMA_Q(1, 1, avB, bvB); PRIO0(); \
  if (st_) { LDB_GRP(bvB, 1, pB + 128); SB0(); } \
  if (st_) { asm volatile("s_waitcnt vmcnt(0)" ::: "memory"); } \
  BAR(); \
  if (st_) { LDA_GRP((c) ^ 1, 0, avA); SB0(); pB += 128; } \
} while (0)

#pragma unroll 1
  for (int sub = 0; sub < 2; ++sub) {
    int m0 = (bp * 2 + sub) * BM;
    const signed char* gA = A + (size_t)(m0 + (t >> 3)) * KDIM + scol;
    const signed char* pB = pBbase;

#pragma unroll
    for (int i = 0; i < 8; ++i)
#pragma unroll
      for (int j = 0; j < 4; ++j) acc[i][j] = (i32x4){0, 0, 0, 0};

    // Stage A tile 0 into buf0; drain; BAR; pre-issue entry set [bvA4 bvB4 avA8].
    STG_A(0, 0, 0); STG_A(0, 0, 64); STG_A(0, 0, 128); STG_A(0, 0, 192);
    asm volatile("s_waitcnt vmcnt(0)" ::: "memory");
    BAR();
    LDB_GRP(bvA, 0, pB); SB0();
    LDB_GRP(bvB, 1, pB); SB0();
    LDA_GRP(0, 0, avA); SB0();

#pragma unroll 1
    for (int kt = 0; kt < NKT; kt += 2) {
      TILE(0, kt);
      TILE(1, kt + 1);
    }

    // Epilogue: C/D col = lane&15, row = (lane>>4)*4 + reg; stores fly async.
    float bvv[4];
#pragma unroll
    for (int fn = 0; fn < 4; ++fn) bvv[fn] = bias[n0 + wn * 64 + fn * 16 + lr];
#pragma unroll
    for (int fm = 0; fm < 8; ++fm) {
      int row0 = m0 + wm * 128 + fm * 16 + lk * 4;
      float sx_[4];
#pragma unroll
      for (int r = 0; r < 4; ++r) sx_[r] = sxr[row0 + r] * sw;
#pragma unroll
      for (int fn = 0; fn < 4; ++fn) {
        int col = n0 + wn * 64 + fn * 16 + lr;
#pragma unroll
        for (int r = 0; r < 4; ++r)
          C[(size_t)(row0 + r) * NDIM + col] = (float)acc[fm][fn][r] * sx_[r] + bvv[fn];
      }
    }
    if (sub == 0) BAR();   // all waves' LDS reads done -> safe to re-stage buf0
  }
#undef TILE
#undef MMA_Q
#undef LDB_GRP
#undef LDA_GRP
#undef STG_A
#undef PRIO1
#undef PRIO0
#undef SB0
#undef BAR
}

// ---- exact-f32 fallback (used only if ws too small) ----
__global__ __launch_bounds__(256) void toep_f32_fallback(
    const float* __restrict__ X, const float* __restrict__ P,
    const float* __restrict__ bias, float* __restrict__ C)
{
  constexpr int TM = 64, TN = 64, TK = 32;
  __shared__ float xs[TM][TK + 1];
  __shared__ float win[TN + TK];
  int bm = blockIdx.x / (NDIM / TN);
  int bn = blockIdx.x % (NDIM / TN);
  int m0 = bm * TM, n0 = bn * TN;
  int t = (int)threadIdx.x;
  int tx = t & 15, ty = t >> 4;
  float acc[4][4] = {};
  for (int k0 = 0; k0 < KDIM; k0 += TK) {
    __syncthreads();
    for (int i = t; i < TM * TK; i += 256) {
      int r = i >> 5, c = i & 31;
      xs[r][c] = X[(size_t)(m0 + r) * KDIM + k0 + c];
    }
    if (t < TN + TK - 1) win[t] = P[(NDIM - 1) - n0 - (TN - 1) + k0 + t];
    __syncthreads();
    for (int kk = 0; kk < TK; ++kk) {
      float xv[4];
#pragma unroll
      for (int i = 0; i < 4; ++i) xv[i] = xs[ty * 4 + i][kk];
#pragma unroll
      for (int j = 0; j < 4; ++j) {
        float wv = win[kk + (TN - 1) - (tx * 4 + j)];
#pragma unroll
        for (int i = 0; i < 4; ++i) acc[i][j] += xv[i] * wv;
      }
    }
  }
#pragma unroll
  for (int i = 0; i < 4; ++i)
#pragma unroll
    for (int j = 0; j < 4; ++j)
      C[(size_t)(m0 + ty * 4 + i) * NDIM + n0 + tx * 4 + j] = acc[i][j] + bias[n0 + tx * 4 + j];
}

extern "C" void kernel_launch(void* const* d_in, const int* in_sizes, int n_in,
                              void* d_out, int out_size, void* d_ws, size_t ws_size,
                              hipStream_t stream) {
  const float* x = (const float*)d_in[0];
  const float* params = (const float*)d_in[1];
  const float* bias = (const float*)d_in[2];
  float* out = (float*)d_out;

  const size_t xq_off = 0;
  const size_t pq_off = (size_t)MDIM * KDIM;               // 32 MiB
  const size_t sx_off = pq_off + 16 * REP_CH * 16 + 64;
  const size_t sw_off = sx_off + (size_t)MDIM * 4;
  const size_t need = sw_off + 64;

  if (ws_size >= need) {
    signed char* xq = (signed char*)d_ws + xq_off;
    i32x4* rep16 = (i32x4*)((char*)d_ws + pq_off);
    float* sxr = (float*)((char*)d_ws + sx_off);
    float* swbuf = (float*)((char*)d_ws + sw_off);
    prep_kernel<<<1, 256, 0, stream>>>(params, swbuf, rep16);
    quant_x_kernel<<<MDIM, 256, 0, stream>>>(x, xq, sxr);
    toep_gemm_i8<<<(MDIM / BM / 2) * (NDIM / BN), 512, 0, stream>>>(xq, rep16, bias, sxr, swbuf, out);
  } else {
    toep_f32_fallback<<<(MDIM / 64) * (NDIM / 64), 256, 0, stream>>>(x, params, bias, out);
  }
}

// Round 16
// 145.464 us; speedup vs baseline: 1.0598x; 1.0598x over previous
//
#include <hip/hip_runtime.h>

typedef __attribute__((ext_vector_type(4))) int i32x4;

#define AS1 __attribute__((address_space(1)))
#define AS3 __attribute__((address_space(3)))

constexpr int MDIM = 8192;   // batch
constexpr int NDIM = 4096;   // out features
constexpr int KDIM = 4096;   // in features

constexpr int BM = 256, BN = 256, BKB = 128;   // BKB = K-bytes (=128 i8) per tile
constexpr int NKT = KDIM / BKB;                // 32
constexpr int REP_CH = 528;                    // global table: 16-B chunks per replica
constexpr int WIN_CH = 273;                    // LDS window: 272 data chunks + 1 pad

__device__ __forceinline__ void gld_lds16(const signed char* g, signed char* l) {
  __builtin_amdgcn_global_load_lds((const AS1 void*)g, (AS3 void*)l, 16, 0, 0);
}

__device__ __forceinline__ int q8(float v, float inv) {
  return __float2int_rn(v * inv);
}

// ---- fused: per-row x quantization (all blocks) + prep (block 0 only) ----
// quant: one block per row of x. block 0 additionally builds swbuf + rep16
// (consumed only by the GEMM, which waits for this whole kernel).
__global__ __launch_bounds__(256) void quant_x_prep_kernel(
    const float* __restrict__ x, signed char* __restrict__ xq, float* __restrict__ sxr,
    const float* __restrict__ params, float* __restrict__ swbuf,
    i32x4* __restrict__ rep16) {
  __shared__ float red[4];
  __shared__ signed char pql[8480];   // used by block 0's prep phase only
  int row = (int)blockIdx.x;
  int t = (int)threadIdx.x;

  // --- quant phase (every block) ---
  {
    const float4* px = (const float4*)(x + (size_t)row * KDIM) + t * 4;
    float4 v[4];
#pragma unroll
    for (int i = 0; i < 4; ++i) v[i] = px[i];
    float m = 0.f;
#pragma unroll
    for (int i = 0; i < 4; ++i)
      m = fmaxf(fmaxf(fmaxf(fabsf(v[i].x), fabsf(v[i].y)), fmaxf(fabsf(v[i].z), fabsf(v[i].w))), m);
#pragma unroll
    for (int off = 32; off >= 1; off >>= 1) m = fmaxf(m, __shfl_xor(m, off));
    if ((t & 63) == 0) red[t >> 6] = m;
    __syncthreads();
    m = fmaxf(fmaxf(red[0], red[1]), fmaxf(red[2], red[3]));
    m = fmaxf(m, 1e-30f);
    float inv = 127.0f / m;
    if (t == 0) sxr[row] = m * (1.0f / 127.0f);
    i32x4 w;
#pragma unroll
    for (int i = 0; i < 4; ++i) {
      int q0 = q8(v[i].x, inv), q1 = q8(v[i].y, inv), q2 = q8(v[i].z, inv), q3 = q8(v[i].w, inv);
      w[i] = (q0 & 0xff) | ((q1 & 0xff) << 8) | ((q2 & 0xff) << 16) | ((q3 & 0xff) << 24);
    }
    *(i32x4*)(xq + (size_t)row * KDIM + t * 16) = w;
  }

  // --- prep phase (block 0 only): swbuf[0] = max|params|/127; rep16 replicas ---
  if (row != 0) return;
  __syncthreads();   // red[] reuse
  {
    float m = 0.f;
    for (int i = t; i < NDIM + KDIM - 1; i += 256) m = fmaxf(m, fabsf(params[i]));
#pragma unroll
    for (int off = 32; off >= 1; off >>= 1) m = fmaxf(m, __shfl_xor(m, off));
    if ((t & 63) == 0) red[t >> 6] = m;
    __syncthreads();
    m = fmaxf(fmaxf(red[0], red[1]), fmaxf(red[2], red[3]));
    m = fmaxf(m, 1e-30f);
    float inv = 127.0f / m;
    if (t == 0) swbuf[0] = m * (1.0f / 127.0f);
    for (int i = t; i < 8480; i += 256)
      pql[i] = (i < NDIM + KDIM - 1) ? (signed char)q8(params[i], inv) : (signed char)0;
    __syncthreads();
    for (int idx = t; idx < 16 * REP_CH; idx += 256) {
      int r = idx / REP_CH, j = idx - r * REP_CH;
      const signed char* s = &pql[16 * j + r];
      i32x4 w;
#pragma unroll
      for (int d = 0; d < 4; ++d) {
        int b0 = (unsigned char)s[4 * d + 0];
        int b1 = (unsigned char)s[4 * d + 1];
        int b2 = (unsigned char)s[4 * d + 2];
        int b3 = (unsigned char)s[4 * d + 3];
        w[d] = b0 | (b1 << 8) | (b2 << 16) | (b3 << 24);
      }
      rep16[idx] = w;
    }
  }
}

// ========== 256x256 i8 GEMM, persistent-pair: 2 M-subtiles per block ==========
// R14 (best measured variant), bit-identical: R13's K-loop/schedule; each block
// (256 total = 1/CU) does bm = 2p, 2p+1 at one n0; pq window staged once;
// sub0's C-stores drain under sub1's compute.
__global__ __launch_bounds__(512, 2) void toep_gemm_i8(
    const signed char* __restrict__ A,
    const i32x4* __restrict__ rep16,
    const float* __restrict__ bias,
    const float* __restrict__ sxr,
    const float* __restrict__ swbuf,
    float* __restrict__ C)
{
  __shared__ signed char sA[2][BM * BKB];          // 65536 B
  __shared__ signed char sPQ[16 * WIN_CH * 16];    // 69888 B

  constexpr int NBN = NDIM / BN;   // 16
  constexpr int NWG = (MDIM / BM / 2) * NBN;   // 256 (divisible by 8 -> bijective swizzle)
  int bid = (int)blockIdx.x;
  int swz = (bid & 7) * (NWG >> 3) + (bid >> 3);
  int bp = swz >> 4;              // M-pair index [0,16)
  int bn = swz & 15;
  int n0 = bn * BN;

  int t = (int)threadIdx.x;
  int lane = t & 63, wid = t >> 6;
  int wm = wid >> 2, wn = wid & 3;     // 2 (M) x 4 (N) waves; 128x64 per wave
  int lr = lane & 15, lk = lane >> 4;

  int scol = (((t & 7) ^ ((t >> 3) & 7)) << 4);   // bytes

  int aswz = (lr & 7) << 4;
  int c0 = (lk * 16) ^ aswz;        // k-bytes 0..63
  int c1 = (64 + lk * 16) ^ aswz;   // k-bytes 64..127

  int j0 = (3840 - n0) >> 4;
  int idx0 = 4095 - (n0 + wn * 64 + lr) + lk * 16;
  const signed char* pBbase = &sPQ[((idx0 & 15) * WIN_CH + ((idx0 >> 4) - j0) - 3) * 16];

  i32x4 avA[4][2], avB[4][2];
  i32x4 bvA[2][2], bvB[2][2];
  i32x4 acc[8][4];

#define STG_A(c, kt, R0) gld_lds16(gA + (size_t)(R0) * KDIM + (kt) * BKB, &sA[c][(R0) * BKB + t * 16])

#define LDA_GRP(c, msub, AV) do { \
  _Pragma("unroll") \
  for (int mi = 0; mi < 4; ++mi) { \
    const signed char* p_ = &sA[c][(wm * 128 + (msub) * 64 + mi * 16 + lr) * BKB]; \
    AV[mi][0] = *(const i32x4*)(p_ + c0); \
    AV[mi][1] = *(const i32x4*)(p_ + c1); \
  } } while (0)

#define LDB_GRP(BV, NSUB, PBP) do { \
  _Pragma("unroll") \
  for (int ni = 0; ni < 2; ++ni) \
    _Pragma("unroll") \
    for (int h = 0; h < 2; ++h) \
      BV[ni][h] = *(const i32x4*)((PBP) + (3 - 2 * (NSUB) - ni + 4 * h) * 16); \
} while (0)

#define MMA_Q(msub, nsub, AV, BV) do { \
  __builtin_amdgcn_s_setprio(1); \
  _Pragma("unroll") \
  for (int mi = 0; mi < 4; ++mi) \
    _Pragma("unroll") \
    for (int ni = 0; ni < 2; ++ni) { \
      acc[(msub) * 4 + mi][(nsub) * 2 + ni] = __builtin_amdgcn_mfma_i32_16x16x64_i8( \
          AV[mi][0], BV[ni][0], acc[(msub) * 4 + mi][(nsub) * 2 + ni], 0, 0, 0); \
      acc[(msub) * 4 + mi][(nsub) * 2 + ni] = __builtin_amdgcn_mfma_i32_16x16x64_i8( \
          AV[mi][1], BV[ni][1], acc[(msub) * 4 + mi][(nsub) * 2 + ni], 0, 0, 0); \
    } \
  __builtin_amdgcn_s_setprio(0); \
} while (0)

#define SB0() __builtin_amdgcn_sched_barrier(0)
#define BAR() __builtin_amdgcn_s_barrier()

  // Stage pq window ONCE per block (both subtiles share n0).
  for (int s = 0; s < 9; ++s) {
    int cc = s * 512 + t;
    if (cc < 16 * WIN_CH) {
      int rr = (int)(((unsigned long long)(unsigned)cc * 15732791ull) >> 32);  // cc/273
      int jj = cc - rr * WIN_CH;
      gld_lds16((const signed char*)(rep16 + rr * REP_CH + j0 + jj), &sPQ[cc * 16]);
    }
  }

  float sw = swbuf[0];

#define TILE(c, kt) do { \
  const bool st_ = (kt) + 1 < NKT; \
  LDB_GRP(bvB, 1, pB); SB0(); \
  if (st_) { STG_A((c) ^ 1, (kt) + 1, 0); STG_A((c) ^ 1, (kt) + 1, 64); \
             STG_A((c) ^ 1, (kt) + 1, 128); STG_A((c) ^ 1, (kt) + 1, 192); SB0(); } \
  asm volatile("s_waitcnt lgkmcnt(4)" ::: "memory"); SB0(); \
  MMA_Q(0, 0, avA, bvA); \
  LDA_GRP(c, 1, avB); SB0(); \
  asm volatile("s_waitcnt lgkmcnt(8)" ::: "memory"); SB0(); \
  MMA_Q(0, 1, avA, bvB); \
  asm volatile("s_waitcnt lgkmcnt(0)" ::: "memory"); SB0(); \
  MMA_Q(1, 0, avB, bvA); \
  if (st_) { LDB_GRP(bvA, 0, pB + 128); SB0(); } \
  if (st_) { asm volatile("s_waitcnt vmcnt(0)" ::: "memory"); } \
  BAR(); \
  if (st_) { LDA_GRP((c) ^ 1, 0, avA); SB0(); pB += 128; } \
  MMA_Q(1, 1, avB, bvB); \
} while (0)

#pragma unroll 1
  for (int sub = 0; sub < 2; ++sub) {
    int m0 = (bp * 2 + sub) * BM;
    const signed char* gA = A + (size_t)(m0 + (t >> 3)) * KDIM + scol;
    const signed char* pB = pBbase;

#pragma unroll
    for (int i = 0; i < 8; ++i)
#pragma unroll
      for (int j = 0; j < 4; ++j) acc[i][j] = (i32x4){0, 0, 0, 0};

    // Stage A tile 0 into buf0; drain; BAR; pre-issue entry set [bvA4][avA8].
    STG_A(0, 0, 0); STG_A(0, 0, 64); STG_A(0, 0, 128); STG_A(0, 0, 192);
    asm volatile("s_waitcnt vmcnt(0)" ::: "memory");
    BAR();
    LDB_GRP(bvA, 0, pB); SB0();
    LDA_GRP(0, 0, avA); SB0();   // DS FIFO: [bvA:4][avA:8]

#pragma unroll 1
    for (int kt = 0; kt < NKT; kt += 2) {
      TILE(0, kt);
      TILE(1, kt + 1);
    }

    // Epilogue: C/D col = lane&15, row = (lane>>4)*4 + reg; stores fly async.
    float bvv[4];
#pragma unroll
    for (int fn = 0; fn < 4; ++fn) bvv[fn] = bias[n0 + wn * 64 + fn * 16 + lr];
#pragma unroll
    for (int fm = 0; fm < 8; ++fm) {
      int row0 = m0 + wm * 128 + fm * 16 + lk * 4;
      float sx_[4];
#pragma unroll
      for (int r = 0; r < 4; ++r) sx_[r] = sxr[row0 + r] * sw;
#pragma unroll
      for (int fn = 0; fn < 4; ++fn) {
        int col = n0 + wn * 64 + fn * 16 + lr;
#pragma unroll
        for (int r = 0; r < 4; ++r)
          C[(size_t)(row0 + r) * NDIM + col] = (float)acc[fm][fn][r] * sx_[r] + bvv[fn];
      }
    }
    if (sub == 0) BAR();   // all waves' LDS reads done -> safe to re-stage buf0
  }
#undef TILE
#undef MMA_Q
#undef LDB_GRP
#undef LDA_GRP
#undef STG_A
#undef SB0
#undef BAR
}

// ---- exact-f32 fallback (used only if ws too small) ----
__global__ __launch_bounds__(256) void toep_f32_fallback(
    const float* __restrict__ X, const float* __restrict__ P,
    const float* __restrict__ bias, float* __restrict__ C)
{
  constexpr int TM = 64, TN = 64, TK = 32;
  __shared__ float xs[TM][TK + 1];
  __shared__ float win[TN + TK];
  int bm = blockIdx.x / (NDIM / TN);
  int bn = blockIdx.x % (NDIM / TN);
  int m0 = bm * TM, n0 = bn * TN;
  int t = (int)threadIdx.x;
  int tx = t & 15, ty = t >> 4;
  float acc[4][4] = {};
  for (int k0 = 0; k0 < KDIM; k0 += TK) {
    __syncthreads();
    for (int i = t; i < TM * TK; i += 256) {
      int r = i >> 5, c = i & 31;
      xs[r][c] = X[(size_t)(m0 + r) * KDIM + k0 + c];
    }
    if (t < TN + TK - 1) win[t] = P[(NDIM - 1) - n0 - (TN - 1) + k0 + t];
    __syncthreads();
    for (int kk = 0; kk < TK; ++kk) {
      float xv[4];
#pragma unroll
      for (int i = 0; i < 4; ++i) xv[i] = xs[ty * 4 + i][kk];
#pragma unroll
      for (int j = 0; j < 4; ++j) {
        float wv = win[kk + (TN - 1) - (tx * 4 + j)];
#pragma unroll
        for (int i = 0; i < 4; ++i) acc[i][j] += xv[i] * wv;
      }
    }
  }
#pragma unroll
  for (int i = 0; i < 4; ++i)
#pragma unroll
    for (int j = 0; j < 4; ++j)
      C[(size_t)(m0 + ty * 4 + i) * NDIM + n0 + tx * 4 + j] = acc[i][j] + bias[n0 + tx * 4 + j];
}

extern "C" void kernel_launch(void* const* d_in, const int* in_sizes, int n_in,
                              void* d_out, int out_size, void* d_ws, size_t ws_size,
                              hipStream_t stream) {
  const float* x = (const float*)d_in[0];
  const float* params = (const float*)d_in[1];
  const float* bias = (const float*)d_in[2];
  float* out = (float*)d_out;

  const size_t xq_off = 0;
  const size_t pq_off = (size_t)MDIM * KDIM;               // 32 MiB
  const size_t sx_off = pq_off + 16 * REP_CH * 16 + 64;
  const size_t sw_off = sx_off + (size_t)MDIM * 4;
  const size_t need = sw_off + 64;

  if (ws_size >= need) {
    signed char* xq = (signed char*)d_ws + xq_off;
    i32x4* rep16 = (i32x4*)((char*)d_ws + pq_off);
    float* sxr = (float*)((char*)d_ws + sx_off);
    float* swbuf = (float*)((char*)d_ws + sw_off);
    quant_x_prep_kernel<<<MDIM, 256, 0, stream>>>(x, xq, sxr, params, swbuf, rep16);
    toep_gemm_i8<<<(MDIM / BM / 2) * (NDIM / BN), 512, 0, stream>>>(xq, rep16, bias, sxr, swbuf, out);
  } else {
    toep_f32_fallback<<<(MDIM / 64) * (NDIM / 64), 256, 0, stream>>>(x, params, bias, out);
  }
}

// Round 17
// 145.281 us; speedup vs baseline: 1.0611x; 1.0013x over previous
//
#include <hip/hip_runtime.h>

typedef __attribute__((ext_vector_type(4))) int i32x4;

#define AS1 __attribute__((address_space(1)))
#define AS3 __attribute__((address_space(3)))

constexpr int MDIM = 8192;   // batch
constexpr int NDIM = 4096;   // out features
constexpr int KDIM = 4096;   // in features

constexpr int BM = 256, BN = 256, BKB = 128;   // BKB = K-bytes (=128 i8) per tile
constexpr int NKT = KDIM / BKB;                // 32
constexpr int REP_CH = 528;                    // global table: 16-B chunks per replica
constexpr int WIN_CH = 273;                    // LDS window: 272 data chunks + 1 pad

__device__ __forceinline__ void gld_lds16(const signed char* g, signed char* l) {
  __builtin_amdgcn_global_load_lds((const AS1 void*)g, (AS3 void*)l, 16, 0, 0);
}

__device__ __forceinline__ int q8(float v, float inv) {
  return __float2int_rn(v * inv);
}

// ---- fused: per-row x quantization (all blocks) + prep (block 0 only) ----
__global__ __launch_bounds__(256) void quant_x_prep_kernel(
    const float* __restrict__ x, signed char* __restrict__ xq, float* __restrict__ sxr,
    const float* __restrict__ params, float* __restrict__ swbuf,
    i32x4* __restrict__ rep16) {
  __shared__ float red[4];
  __shared__ signed char pql[8480];   // used by block 0's prep phase only
  int row = (int)blockIdx.x;
  int t = (int)threadIdx.x;

  // --- quant phase (every block) ---
  {
    const float4* px = (const float4*)(x + (size_t)row * KDIM) + t * 4;
    float4 v[4];
#pragma unroll
    for (int i = 0; i < 4; ++i) v[i] = px[i];
    float m = 0.f;
#pragma unroll
    for (int i = 0; i < 4; ++i)
      m = fmaxf(fmaxf(fmaxf(fabsf(v[i].x), fabsf(v[i].y)), fmaxf(fabsf(v[i].z), fabsf(v[i].w))), m);
#pragma unroll
    for (int off = 32; off >= 1; off >>= 1) m = fmaxf(m, __shfl_xor(m, off));
    if ((t & 63) == 0) red[t >> 6] = m;
    __syncthreads();
    m = fmaxf(fmaxf(red[0], red[1]), fmaxf(red[2], red[3]));
    m = fmaxf(m, 1e-30f);
    float inv = 127.0f / m;
    if (t == 0) sxr[row] = m * (1.0f / 127.0f);
    i32x4 w;
#pragma unroll
    for (int i = 0; i < 4; ++i) {
      int q0 = q8(v[i].x, inv), q1 = q8(v[i].y, inv), q2 = q8(v[i].z, inv), q3 = q8(v[i].w, inv);
      w[i] = (q0 & 0xff) | ((q1 & 0xff) << 8) | ((q2 & 0xff) << 16) | ((q3 & 0xff) << 24);
    }
    *(i32x4*)(xq + (size_t)row * KDIM + t * 16) = w;
  }

  // --- prep phase (block 0 only): swbuf[0] = max|params|/127; rep16 replicas ---
  if (row != 0) return;
  __syncthreads();   // red[] reuse
  {
    float m = 0.f;
    for (int i = t; i < NDIM + KDIM - 1; i += 256) m = fmaxf(m, fabsf(params[i]));
#pragma unroll
    for (int off = 32; off >= 1; off >>= 1) m = fmaxf(m, __shfl_xor(m, off));
    if ((t & 63) == 0) red[t >> 6] = m;
    __syncthreads();
    m = fmaxf(fmaxf(red[0], red[1]), fmaxf(red[2], red[3]));
    m = fmaxf(m, 1e-30f);
    float inv = 127.0f / m;
    if (t == 0) swbuf[0] = m * (1.0f / 127.0f);
    for (int i = t; i < 8480; i += 256)
      pql[i] = (i < NDIM + KDIM - 1) ? (signed char)q8(params[i], inv) : (signed char)0;
    __syncthreads();
    for (int idx = t; idx < 16 * REP_CH; idx += 256) {
      int r = idx / REP_CH, j = idx - r * REP_CH;
      const signed char* s = &pql[16 * j + r];
      i32x4 w;
#pragma unroll
      for (int d = 0; d < 4; ++d) {
        int b0 = (unsigned char)s[4 * d + 0];
        int b1 = (unsigned char)s[4 * d + 1];
        int b2 = (unsigned char)s[4 * d + 2];
        int b3 = (unsigned char)s[4 * d + 3];
        w[d] = b0 | (b1 << 8) | (b2 << 16) | (b3 << 24);
      }
      rep16[idx] = w;
    }
  }
}

// ========== 256x256 i8 GEMM, persistent-pair, replica-row-permuted pq window ==========
// R14/R16 GEMM with one change: replica r is stored in PHYSICAL window row
// rho(r) = r<8 ? r : 8+((r+1)&7). The colliding replica pair (r, r+8) — same
// chunk column, row-stride 273 == 1 (mod 8) -> same bank — now lands in rows
// differing by 1 (mod 8) -> bank offset 4, disjoint b128 spans. Bytes unchanged.
__global__ __launch_bounds__(512, 2) void toep_gemm_i8(
    const signed char* __restrict__ A,
    const i32x4* __restrict__ rep16,
    const float* __restrict__ bias,
    const float* __restrict__ sxr,
    const float* __restrict__ swbuf,
    float* __restrict__ C)
{
  __shared__ signed char sA[2][BM * BKB];          // 65536 B
  __shared__ signed char sPQ[16 * WIN_CH * 16];    // 69888 B

  constexpr int NBN = NDIM / BN;   // 16
  constexpr int NWG = (MDIM / BM / 2) * NBN;   // 256 (divisible by 8 -> bijective swizzle)
  int bid = (int)blockIdx.x;
  int swz = (bid & 7) * (NWG >> 3) + (bid >> 3);
  int bp = swz >> 4;              // M-pair index [0,16)
  int bn = swz & 15;
  int n0 = bn * BN;

  int t = (int)threadIdx.x;
  int lane = t & 63, wid = t >> 6;
  int wm = wid >> 2, wn = wid & 3;     // 2 (M) x 4 (N) waves; 128x64 per wave
  int lr = lane & 15, lk = lane >> 4;

  int scol = (((t & 7) ^ ((t >> 3) & 7)) << 4);   // bytes

  int aswz = (lr & 7) << 4;
  int c0 = (lk * 16) ^ aswz;        // k-bytes 0..63
  int c1 = (64 + lk * 16) ^ aswz;   // k-bytes 64..127

  int j0 = (3840 - n0) >> 4;
  int idx0 = 4095 - (n0 + wn * 64 + lr) + lk * 16;
  int rrep = idx0 & 15;
  int prow = rrep < 8 ? rrep : 8 + ((rrep + 1) & 7);   // rho(r)
  const signed char* pBbase = &sPQ[(prow * WIN_CH + ((idx0 >> 4) - j0) - 3) * 16];

  i32x4 avA[4][2], avB[4][2];
  i32x4 bvA[2][2], bvB[2][2];
  i32x4 acc[8][4];

#define STG_A(c, kt, R0) gld_lds16(gA + (size_t)(R0) * KDIM + (kt) * BKB, &sA[c][(R0) * BKB + t * 16])

#define LDA_GRP(c, msub, AV) do { \
  _Pragma("unroll") \
  for (int mi = 0; mi < 4; ++mi) { \
    const signed char* p_ = &sA[c][(wm * 128 + (msub) * 64 + mi * 16 + lr) * BKB]; \
    AV[mi][0] = *(const i32x4*)(p_ + c0); \
    AV[mi][1] = *(const i32x4*)(p_ + c1); \
  } } while (0)

#define LDB_GRP(BV, NSUB, PBP) do { \
  _Pragma("unroll") \
  for (int ni = 0; ni < 2; ++ni) \
    _Pragma("unroll") \
    for (int h = 0; h < 2; ++h) \
      BV[ni][h] = *(const i32x4*)((PBP) + (3 - 2 * (NSUB) - ni + 4 * h) * 16); \
} while (0)

#define MMA_Q(msub, nsub, AV, BV) do { \
  __builtin_amdgcn_s_setprio(1); \
  _Pragma("unroll") \
  for (int mi = 0; mi < 4; ++mi) \
    _Pragma("unroll") \
    for (int ni = 0; ni < 2; ++ni) { \
      acc[(msub) * 4 + mi][(nsub) * 2 + ni] = __builtin_amdgcn_mfma_i32_16x16x64_i8( \
          AV[mi][0], BV[ni][0], acc[(msub) * 4 + mi][(nsub) * 2 + ni], 0, 0, 0); \
      acc[(msub) * 4 + mi][(nsub) * 2 + ni] = __builtin_amdgcn_mfma_i32_16x16x64_i8( \
          AV[mi][1], BV[ni][1], acc[(msub) * 4 + mi][(nsub) * 2 + ni], 0, 0, 0); \
    } \
  __builtin_amdgcn_s_setprio(0); \
} while (0)

#define SB0() __builtin_amdgcn_sched_barrier(0)
#define BAR() __builtin_amdgcn_s_barrier()

  // Stage pq window ONCE per block; physical row pr sources replica rho^-1(pr).
  for (int s = 0; s < 9; ++s) {
    int cc = s * 512 + t;
    if (cc < 16 * WIN_CH) {
      int pr = (int)(((unsigned long long)(unsigned)cc * 15732791ull) >> 32);  // cc/273
      int jj = cc - pr * WIN_CH;
      int sr = pr < 8 ? pr : 8 + ((pr + 7) & 7);   // rho^-1
      gld_lds16((const signed char*)(rep16 + sr * REP_CH + j0 + jj), &sPQ[cc * 16]);
    }
  }

  float sw = swbuf[0];

#define TILE(c, kt) do { \
  const bool st_ = (kt) + 1 < NKT; \
  LDB_GRP(bvB, 1, pB); SB0(); \
  if (st_) { STG_A((c) ^ 1, (kt) + 1, 0); STG_A((c) ^ 1, (kt) + 1, 64); \
             STG_A((c) ^ 1, (kt) + 1, 128); STG_A((c) ^ 1, (kt) + 1, 192); SB0(); } \
  asm volatile("s_waitcnt lgkmcnt(4)" ::: "memory"); SB0(); \
  MMA_Q(0, 0, avA, bvA); \
  LDA_GRP(c, 1, avB); SB0(); \
  asm volatile("s_waitcnt lgkmcnt(8)" ::: "memory"); SB0(); \
  MMA_Q(0, 1, avA, bvB); \
  asm volatile("s_waitcnt lgkmcnt(0)" ::: "memory"); SB0(); \
  MMA_Q(1, 0, avB, bvA); \
  if (st_) { LDB_GRP(bvA, 0, pB + 128); SB0(); } \
  if (st_) { asm volatile("s_waitcnt vmcnt(0)" ::: "memory"); } \
  BAR(); \
  if (st_) { LDA_GRP((c) ^ 1, 0, avA); SB0(); pB += 128; } \
  MMA_Q(1, 1, avB, bvB); \
} while (0)

#pragma unroll 1
  for (int sub = 0; sub < 2; ++sub) {
    int m0 = (bp * 2 + sub) * BM;
    const signed char* gA = A + (size_t)(m0 + (t >> 3)) * KDIM + scol;
    const signed char* pB = pBbase;

#pragma unroll
    for (int i = 0; i < 8; ++i)
#pragma unroll
      for (int j = 0; j < 4; ++j) acc[i][j] = (i32x4){0, 0, 0, 0};

    // Stage A tile 0 into buf0; drain; BAR; pre-issue entry set [bvA4][avA8].
    STG_A(0, 0, 0); STG_A(0, 0, 64); STG_A(0, 0, 128); STG_A(0, 0, 192);
    asm volatile("s_waitcnt vmcnt(0)" ::: "memory");
    BAR();
    LDB_GRP(bvA, 0, pB); SB0();
    LDA_GRP(0, 0, avA); SB0();   // DS FIFO: [bvA:4][avA:8]

#pragma unroll 1
    for (int kt = 0; kt < NKT; kt += 2) {
      TILE(0, kt);
      TILE(1, kt + 1);
    }

    // Epilogue: C/D col = lane&15, row = (lane>>4)*4 + reg; stores fly async.
    float bvv[4];
#pragma unroll
    for (int fn = 0; fn < 4; ++fn) bvv[fn] = bias[n0 + wn * 64 + fn * 16 + lr];
#pragma unroll
    for (int fm = 0; fm < 8; ++fm) {
      int row0 = m0 + wm * 128 + fm * 16 + lk * 4;
      float sx_[4];
#pragma unroll
      for (int r = 0; r < 4; ++r) sx_[r] = sxr[row0 + r] * sw;
#pragma unroll
      for (int fn = 0; fn < 4; ++fn) {
        int col = n0 + wn * 64 + fn * 16 + lr;
#pragma unroll
        for (int r = 0; r < 4; ++r)
          C[(size_t)(row0 + r) * NDIM + col] = (float)acc[fm][fn][r] * sx_[r] + bvv[fn];
      }
    }
    if (sub == 0) BAR();   // all waves' LDS reads done -> safe to re-stage buf0
  }
#undef TILE
#undef MMA_Q
#undef LDB_GRP
#undef LDA_GRP
#undef STG_A
#undef SB0
#undef BAR
}

// ---- exact-f32 fallback (used only if ws too small) ----
__global__ __launch_bounds__(256) void toep_f32_fallback(
    const float* __restrict__ X, const float* __restrict__ P,
    const float* __restrict__ bias, float* __restrict__ C)
{
  constexpr int TM = 64, TN = 64, TK = 32;
  __shared__ float xs[TM][TK + 1];
  __shared__ float win[TN + TK];
  int bm = blockIdx.x / (NDIM / TN);
  int bn = blockIdx.x % (NDIM / TN);
  int m0 = bm * TM, n0 = bn * TN;
  int t = (int)threadIdx.x;
  int tx = t & 15, ty = t >> 4;
  float acc[4][4] = {};
  for (int k0 = 0; k0 < KDIM; k0 += TK) {
    __syncthreads();
    for (int i = t; i < TM * TK; i += 256) {
      int r = i >> 5, c = i & 31;
      xs[r][c] = X[(size_t)(m0 + r) * KDIM + k0 + c];
    }
    if (t < TN + TK - 1) win[t] = P[(NDIM - 1) - n0 - (TN - 1) + k0 + t];
    __syncthreads();
    for (int kk = 0; kk < TK; ++kk) {
      float xv[4];
#pragma unroll
      for (int i = 0; i < 4; ++i) xv[i] = xs[ty * 4 + i][kk];
#pragma unroll
      for (int j = 0; j < 4; ++j) {
        float wv = win[kk + (TN - 1) - (tx * 4 + j)];
#pragma unroll
        for (int i = 0; i < 4; ++i) acc[i][j] += xv[i] * wv;
      }
    }
  }
#pragma unroll
  for (int i = 0; i < 4; ++i)
#pragma unroll
    for (int j = 0; j < 4; ++j)
      C[(size_t)(m0 + ty * 4 + i) * NDIM + n0 + tx * 4 + j] = acc[i][j] + bias[n0 + tx * 4 + j];
}

extern "C" void kernel_launch(void* const* d_in, const int* in_sizes, int n_in,
                              void* d_out, int out_size, void* d_ws, size_t ws_size,
                              hipStream_t stream) {
  const float* x = (const float*)d_in[0];
  const float* params = (const float*)d_in[1];
  const float* bias = (const float*)d_in[2];
  float* out = (float*)d_out;

  const size_t xq_off = 0;
  const size_t pq_off = (size_t)MDIM * KDIM;               // 32 MiB
  const size_t sx_off = pq_off + 16 * REP_CH * 16 + 64;
  const size_t sw_off = sx_off + (size_t)MDIM * 4;
  const size_t need = sw_off + 64;

  if (ws_size >= need) {
    signed char* xq = (signed char*)d_ws + xq_off;
    i32x4* rep16 = (i32x4*)((char*)d_ws + pq_off);
    float* sxr = (float*)((char*)d_ws + sx_off);
    float* swbuf = (float*)((char*)d_ws + sw_off);
    quant_x_prep_kernel<<<MDIM, 256, 0, stream>>>(x, xq, sxr, params, swbuf, rep16);
    toep_gemm_i8<<<(MDIM / BM / 2) * (NDIM / BN), 512, 0, stream>>>(xq, rep16, bias, sxr, swbuf, out);
  } else {
    toep_f32_fallback<<<(MDIM / 64) * (NDIM / 64), 256, 0, stream>>>(x, params, bias, out);
  }
}